// Round 10
// baseline (342.822 us; speedup 1.0000x reference)
//
#include <hip/hip_runtime.h>
#include <math.h>
#include <stdint.h>

#define Bb 64
#define Ss 512
#define Tt 32
#define H2 1024   // feature dim of h
#define FF 2048   // w1_w row stride
#define ATT 512
#define MM (Bb * Ss)

typedef short bf8 __attribute__((ext_vector_type(8)));   // 8 bf16 MFMA A/B frag
typedef float f4 __attribute__((ext_vector_type(4)));

// fp32 -> bf16 (RNE), bit-level
__device__ __forceinline__ unsigned short f2bf(float f) {
    unsigned u = __float_as_uint(f);
    u = (u + 0x7fffu + ((u >> 16) & 1u)) >> 16;
    return (unsigned short)u;
}

__device__ __forceinline__ void gl_lds16(const void* g, void* l) {
    __builtin_amdgcn_global_load_lds((const __attribute__((address_space(1))) void*)g,
                                     (__attribute__((address_space(3))) void*)l, 16, 0, 0);
}

// fast tanh via v_exp_f32 path; saturates correctly at +-inf
__device__ __forceinline__ float tanh_fast(float x) {
    return 1.0f - 2.0f / (__expf(2.0f * x) + 1.0f);
}

// ---------------------------------------------------------------- prep: init beta/out + ht mean + convw (one launch)
__global__ __launch_bounds__(256) void prep_kernel(
        const float* __restrict__ ht, float* __restrict__ ht_mean,
        const float* __restrict__ w1_w, unsigned short* __restrict__ w1a_bf,
        float* __restrict__ beta, float* __restrict__ out) {
    const int bx = (int)blockIdx.x, tid = (int)threadIdx.x;
    if (bx < 384) {
        // zero beta (32768) then out (65536)
        int i = bx * 256 + tid;
        if (i < Bb * Ss) beta[i] = 0.0f;
        else out[i - Bb * Ss] = 0.0f;
    } else if (bx < 448) {
        // ht mean over T for batch b
        int b = bx - 384;
        const float4* p = (const float4*)(ht + (size_t)b * Tt * H2);
        float4 acc = make_float4(0.f, 0.f, 0.f, 0.f);
        #pragma unroll 4
        for (int t = 0; t < Tt; ++t) {
            float4 v = p[(size_t)t * (H2 / 4) + tid];
            acc.x += v.x; acc.y += v.y; acc.z += v.z; acc.w += v.w;
        }
        const float inv = 1.0f / (float)Tt;
        acc.x *= inv; acc.y *= inv; acc.z *= inv; acc.w *= inv;
        ((float4*)(ht_mean + (size_t)b * H2))[tid] = acc;
    } else {
        // w1a_bf[a][k] = bf16(w1_w[a][k]), k<1024 (strided rows)
        size_t e = ((size_t)(bx - 448) * 256 + tid) * 8;
        int row = (int)(e >> 10);
        int c = (int)(e & 1023);
        const float* src = w1_w + (size_t)row * FF + c;
        float4 a = *(const float4*)(src);
        float4 b = *(const float4*)(src + 4);
        bf8 v = { (short)f2bf(a.x), (short)f2bf(a.y), (short)f2bf(a.z), (short)f2bf(a.w),
                  (short)f2bf(b.x), (short)f2bf(b.y), (short)f2bf(b.z), (short)f2bf(b.w) };
        *(bf8*)(w1a_bf + e) = v;
    }
}

// ---------------------------------------------------------------- c2[b,a] = ht_mean[b].w1_w[a,1024:] + w1_b[a]
__global__ __launch_bounds__(256) void c2_kernel2(const float* __restrict__ ht_mean,
                                                  const float* __restrict__ w1_w,
                                                  const float* __restrict__ w1_b,
                                                  float* __restrict__ c2) {
    __shared__ float hm[H2];
    int b = blockIdx.x;
    for (int i = threadIdx.x; i < H2; i += 256) hm[i] = ht_mean[(size_t)b * H2 + i];
    __syncthreads();
    int a = blockIdx.y * 64 + ((int)threadIdx.x >> 2);
    int q = (int)threadIdx.x & 3;
    const float4* w   = (const float4*)(w1_w + (size_t)a * FF + H2 + q * 256);
    const float4* hm4 = (const float4*)(hm + q * 256);
    float acc = 0.f;
    #pragma unroll 8
    for (int k = 0; k < 64; ++k) {
        float4 wv = w[k]; float4 hv = hm4[k];
        acc += wv.x * hv.x + wv.y * hv.y + wv.z * hv.z + wv.w * hv.w;
    }
    acc += __shfl_xor(acc, 1);
    acc += __shfl_xor(acc, 2);
    if (q == 0) c2[(size_t)b * ATT + a] = acc + w1_b[a];
}

// ---------------------------------------------------------------- h_bf = bf16(h), linear copy
__global__ void convh_kernel(const float* __restrict__ in, unsigned short* __restrict__ out) {
    size_t i = ((size_t)blockIdx.x * 256 + threadIdx.x) * 8;
    float4 a = *(const float4*)(in + i);
    float4 b = *(const float4*)(in + i + 4);
    bf8 v = { (short)f2bf(a.x), (short)f2bf(a.y), (short)f2bf(a.z), (short)f2bf(a.w),
              (short)f2bf(b.x), (short)f2bf(b.y), (short)f2bf(b.z), (short)f2bf(b.w) };
    *(bf8*)(out + i) = v;
}

// ---------------------------------------------------------------- fused GEMM: M=32768, N=512, K=1024
// 128x128 tile, BK=32, 4 waves (2x2), grid 1024, XCD-chunked. THREE LDS buffers, prefetch
// depth 2: step t issues tile t+2, then computes tile t, then waits vmcnt(4) (= tile t+1
// landed, t+2 still in flight) + raw s_barrier. Only the tail (t>=30) drains vmcnt(0).
// Source-swizzled gl_lds staging, LDS 16B-slot swizzle s^((r>>1)&3) (r8-verified: 0 conflicts).
__global__ __launch_bounds__(256, 3) void gemm_p3_kernel(
        const unsigned short* __restrict__ hb, const unsigned short* __restrict__ wb,
        const float* __restrict__ c2, const float* __restrict__ u_w,
        float* __restrict__ beta) {
    __shared__ __align__(16) unsigned short As[3][128 * 32];   // 24 KB
    __shared__ __align__(16) unsigned short Bs[3][128 * 32];   // 24 KB

    const int id = (int)blockIdx.x;                 // 0..1023
    const int wg = (id & 7) * 128 + (id >> 3);      // XCD-chunked (1024 % 8 == 0 -> bijective)
    const int mt = wg >> 2, nt = wg & 3;
    const int m0 = mt * 128, n0 = nt * 128;

    const int tid = (int)threadIdx.x;
    const int wid = tid >> 6, lane = tid & 63;
    const int wr = (wid >> 1) * 64, wc = (wid & 1) * 64;
    const int col = lane & 15, rg = lane >> 4;
    const int rswz = rg ^ ((col >> 1) & 3);         // read slot (row bases are 0 mod 16)

    f4 acc[4][4] = {};

    // staging: row = tid>>2 (0..63; +64 on 2nd call), source slot pre-swizzled
    const int srow = tid >> 2;
    const int sslot = (tid & 3) ^ ((tid >> 3) & 3);
    const unsigned short* Agl = hb + (size_t)(m0 + srow) * H2 + sslot * 8;
    const unsigned short* Bgl = wb + (size_t)(n0 + srow) * H2 + sslot * 8;
    const int ldsb = wid * 512;   // elems; HW adds lane*16B; 2nd 64-row chunk at +2048

    // ---- prologue: stage tiles 0 and 1 (8 loads)
    #pragma unroll
    for (int p = 0; p < 2; ++p) {
        const int k0 = p * 32;
        gl_lds16(Agl + k0,                   &As[p][ldsb]);
        gl_lds16(Agl + k0 + (size_t)64 * H2, &As[p][ldsb + 2048]);
        gl_lds16(Bgl + k0,                   &Bs[p][ldsb]);
        gl_lds16(Bgl + k0 + (size_t)64 * H2, &Bs[p][ldsb + 2048]);
    }
    asm volatile("s_waitcnt vmcnt(4)" ::: "memory");   // tile 0 landed (tile 1 in flight)
    __builtin_amdgcn_s_barrier();

    int cur = 0;
    for (int t = 0; t < 32; ++t) {
        // ---- issue tile t+2 into the third buffer
        if (t < 30) {
            int wrb = cur + 2; if (wrb >= 3) wrb -= 3;
            const int kn = (t + 2) * 32;
            gl_lds16(Agl + kn,                   &As[wrb][ldsb]);
            gl_lds16(Agl + kn + (size_t)64 * H2, &As[wrb][ldsb + 2048]);
            gl_lds16(Bgl + kn,                   &Bs[wrb][ldsb]);
            gl_lds16(Bgl + kn + (size_t)64 * H2, &Bs[wrb][ldsb + 2048]);
        }
        __builtin_amdgcn_sched_barrier(0);   // pin prefetch issues above compute
        // ---- compute tile t
        bf8 av[4], bv[4];
        #pragma unroll
        for (int i = 0; i < 4; ++i) {
            av[i] = *(const bf8*)&As[cur][(wr + i * 16 + col) * 32 + rswz * 8];
            bv[i] = *(const bf8*)&Bs[cur][(wc + i * 16 + col) * 32 + rswz * 8];
        }
        #pragma unroll
        for (int i = 0; i < 4; ++i)
            #pragma unroll
            for (int j = 0; j < 4; ++j)
                acc[i][j] = __builtin_amdgcn_mfma_f32_16x16x32_bf16(av[i], bv[j], acc[i][j], 0, 0, 0);
        // ---- wait only tile t+1's loads (counted), not the just-issued t+2
        if (t < 30) asm volatile("s_waitcnt vmcnt(4)" ::: "memory");
        else        asm volatile("s_waitcnt vmcnt(0)" ::: "memory");
        __builtin_amdgcn_s_barrier();
        cur = (cur == 2) ? 0 : cur + 1;
    }

    // ---- epilogue: beta[m] += sum_n tanh(acc + c2[n]) * u[n] over this wave's 64-col strip
    const int b_idx = mt >> 2;                      // m0 / Ss
    const float* c2b = c2 + (size_t)b_idx * ATT + n0 + wc;
    const float* ub  = u_w + n0 + wc;
    float rp[4][4] = {};
    #pragma unroll
    for (int j = 0; j < 4; ++j) {
        int n = j * 16 + col;
        float cv = c2b[n];
        float uv = ub[n];
        #pragma unroll
        for (int i = 0; i < 4; ++i)
            #pragma unroll
            for (int r = 0; r < 4; ++r)
                rp[i][r] += tanh_fast(acc[i][j][r] + cv) * uv;
    }
    #pragma unroll
    for (int i = 0; i < 4; ++i)
        #pragma unroll
        for (int r = 0; r < 4; ++r) {
            float v = rp[i][r];
            v += __shfl_xor(v, 1);
            v += __shfl_xor(v, 2);
            v += __shfl_xor(v, 4);
            v += __shfl_xor(v, 8);
            if (col == 0)
                atomicAdd(&beta[(size_t)m0 + wr + i * 16 + rg * 4 + r], v);
        }
}

// ---------------------------------------------------------------- fused masked-softmax + weighted sum
// grid (Bb, 8): block (b, sc) recomputes the tiny softmax for batch b (LDS), then
// accumulates its 64-s chunk of s[b,d] = sum_s alpha*h_bf via atomics.
__global__ __launch_bounds__(256) void wsum2_kernel(
        const unsigned short* __restrict__ hb, const float* __restrict__ beta,
        const int* __restrict__ h_mask, float* __restrict__ out) {
    __shared__ float red[8];
    __shared__ float al[64];
    const int b = (int)blockIdx.x;
    const int sc = (int)blockIdx.y;
    const int tid = (int)threadIdx.x;
    const int lane = tid & 63, wave = tid >> 6;

    const float* bp = beta + (size_t)b * Ss;
    const int* mp = h_mask + (size_t)b * Ss;
    float v1 = mp[tid]       ? bp[tid]       : -1e20f;
    float v2 = mp[tid + 256] ? bp[tid + 256] : -1e20f;
    float mx = fmaxf(v1, v2);
    #pragma unroll
    for (int off = 32; off >= 1; off >>= 1) mx = fmaxf(mx, __shfl_xor(mx, off, 64));
    if (lane == 0) red[wave] = mx;
    __syncthreads();
    mx = fmaxf(fmaxf(red[0], red[1]), fmaxf(red[2], red[3]));
    float e1 = __expf(v1 - mx), e2 = __expf(v2 - mx);
    float sm = e1 + e2;
    #pragma unroll
    for (int off = 32; off >= 1; off >>= 1) sm += __shfl_xor(sm, off, 64);
    if (lane == 0) red[4 + wave] = sm;
    __syncthreads();
    const float inv = 1.0f / ((red[4] + red[5]) + (red[6] + red[7]));
    int ls1 = tid - sc * 64, ls2 = tid + 256 - sc * 64;
    if ((unsigned)ls1 < 64u) al[ls1] = e1 * inv;
    if ((unsigned)ls2 < 64u) al[ls2] = e2 * inv;
    __syncthreads();

    const int g = tid >> 7, t = tid & 127;     // s-half (32) x dim-group (8 dims)
    const int d0 = t * 8, si = g * 32;
    const unsigned short* hp = hb + ((size_t)b * Ss + sc * 64 + si) * H2 + d0;
    float acc[8] = {};
    #pragma unroll 4
    for (int s = 0; s < 32; ++s) {
        bf8 v = *(const bf8*)(hp + (size_t)s * H2);
        float a = al[si + s];
        #pragma unroll
        for (int j = 0; j < 8; ++j) {
            float hv = __uint_as_float(((unsigned)(unsigned short)v[j]) << 16);
            acc[j] = fmaf(a, hv, acc[j]);
        }
    }
    #pragma unroll
    for (int j = 0; j < 8; ++j)
        atomicAdd(&out[(size_t)b * H2 + d0 + j], acc[j]);
}

// ---------------------------------------------------------------- launch
extern "C" void kernel_launch(void* const* d_in, const int* in_sizes, int n_in,
                              void* d_out, int out_size, void* d_ws, size_t ws_size,
                              hipStream_t stream) {
    const float* h      = (const float*)d_in[0];
    const int*   h_mask = (const int*)d_in[1];
    const float* ht     = (const float*)d_in[2];
    const float* w1_w   = (const float*)d_in[3];
    const float* w1_b   = (const float*)d_in[4];
    const float* u_w    = (const float*)d_in[5];
    float* out = (float*)d_out;

    float* ws      = (float*)d_ws;
    float* ht_mean = ws;                 // 65536 floats
    float* c2      = ws + 65536;         // 32768
    float* beta    = ws + 98304;         // 32768  -> 524288 B used of first region
    unsigned short* w1a_bf = (unsigned short*)((char*)d_ws + 659456);            // 1 MB
    unsigned short* h_bf   = (unsigned short*)((char*)d_ws + 659456 + 1048576);  // 64 MB (ws-fit proven r2)

    hipLaunchKernelGGL(prep_kernel, dim3(704), dim3(256), 0, stream,
                       ht, ht_mean, w1_w, w1a_bf, beta, out);
    hipLaunchKernelGGL(c2_kernel2, dim3(Bb, 8), dim3(256), 0, stream, ht_mean, w1_w, w1_b, c2);
    hipLaunchKernelGGL(convh_kernel, dim3(16384), dim3(256), 0, stream, h, h_bf);
    hipLaunchKernelGGL(gemm_p3_kernel, dim3((MM / 128) * (ATT / 128)), dim3(256), 0, stream,
                       h_bf, w1a_bf, c2, u_w, beta);
    hipLaunchKernelGGL(wsum2_kernel, dim3(Bb, 8), dim3(256), 0, stream, h_bf, beta, h_mask, out);
}

// Round 14
// 331.841 us; speedup vs baseline: 1.0331x; 1.0331x over previous
//
#include <hip/hip_runtime.h>
#include <math.h>
#include <stdint.h>

#define Bb 64
#define Ss 512
#define Tt 32
#define H2 1024   // feature dim of h
#define FF 2048   // w1_w row stride
#define ATT 512
#define MM (Bb * Ss)

typedef short bf8 __attribute__((ext_vector_type(8)));   // 8 bf16 MFMA A/B frag
typedef float f4 __attribute__((ext_vector_type(4)));
typedef __attribute__((address_space(3))) const unsigned short* lds_cp;

// fp32 -> bf16 (RNE), bit-level
__device__ __forceinline__ unsigned short f2bf(float f) {
    unsigned u = __float_as_uint(f);
    u = (u + 0x7fffu + ((u >> 16) & 1u)) >> 16;
    return (unsigned short)u;
}

__device__ __forceinline__ void gl_lds16(const void* g, void* l) {
    __builtin_amdgcn_global_load_lds((const __attribute__((address_space(1))) void*)g,
                                     (__attribute__((address_space(3))) void*)l, 16, 0, 0);
}

// fast tanh via v_exp_f32 path; saturates correctly at +-inf
__device__ __forceinline__ float tanh_fast(float x) {
    return 1.0f - 2.0f / (__expf(2.0f * x) + 1.0f);
}

// ---------------------------------------------------------------- prep: init beta/out + ht mean + convw (one launch)
__global__ __launch_bounds__(256) void prep_kernel(
        const float* __restrict__ ht, float* __restrict__ ht_mean,
        const float* __restrict__ w1_w, unsigned short* __restrict__ w1a_bf,
        float* __restrict__ beta, float* __restrict__ out) {
    const int bx = (int)blockIdx.x, tid = (int)threadIdx.x;
    if (bx < 384) {
        int i = bx * 256 + tid;
        if (i < Bb * Ss) beta[i] = 0.0f;
        else out[i - Bb * Ss] = 0.0f;
    } else if (bx < 448) {
        int b = bx - 384;
        const float4* p = (const float4*)(ht + (size_t)b * Tt * H2);
        float4 acc = make_float4(0.f, 0.f, 0.f, 0.f);
        #pragma unroll 4
        for (int t = 0; t < Tt; ++t) {
            float4 v = p[(size_t)t * (H2 / 4) + tid];
            acc.x += v.x; acc.y += v.y; acc.z += v.z; acc.w += v.w;
        }
        const float inv = 1.0f / (float)Tt;
        acc.x *= inv; acc.y *= inv; acc.z *= inv; acc.w *= inv;
        ((float4*)(ht_mean + (size_t)b * H2))[tid] = acc;
    } else {
        size_t e = ((size_t)(bx - 448) * 256 + tid) * 8;
        int row = (int)(e >> 10);
        int c = (int)(e & 1023);
        const float* src = w1_w + (size_t)row * FF + c;
        float4 a = *(const float4*)(src);
        float4 b = *(const float4*)(src + 4);
        bf8 v = { (short)f2bf(a.x), (short)f2bf(a.y), (short)f2bf(a.z), (short)f2bf(a.w),
                  (short)f2bf(b.x), (short)f2bf(b.y), (short)f2bf(b.z), (short)f2bf(b.w) };
        *(bf8*)(w1a_bf + e) = v;
    }
}

// ---------------------------------------------------------------- c2[b,a] = ht_mean[b].w1_w[a,1024:] + w1_b[a]
__global__ __launch_bounds__(256) void c2_kernel2(const float* __restrict__ ht_mean,
                                                  const float* __restrict__ w1_w,
                                                  const float* __restrict__ w1_b,
                                                  float* __restrict__ c2) {
    __shared__ float hm[H2];
    int b = blockIdx.x;
    for (int i = threadIdx.x; i < H2; i += 256) hm[i] = ht_mean[(size_t)b * H2 + i];
    __syncthreads();
    int a = blockIdx.y * 64 + ((int)threadIdx.x >> 2);
    int q = (int)threadIdx.x & 3;
    const float4* w   = (const float4*)(w1_w + (size_t)a * FF + H2 + q * 256);
    const float4* hm4 = (const float4*)(hm + q * 256);
    float acc = 0.f;
    #pragma unroll 8
    for (int k = 0; k < 64; ++k) {
        float4 wv = w[k]; float4 hv = hm4[k];
        acc += wv.x * hv.x + wv.y * hv.y + wv.z * hv.z + wv.w * hv.w;
    }
    acc += __shfl_xor(acc, 1);
    acc += __shfl_xor(acc, 2);
    if (q == 0) c2[(size_t)b * ATT + a] = acc + w1_b[a];
}

// ---------------------------------------------------------------- h_bf = bf16(h), linear copy
__global__ void convh_kernel(const float* __restrict__ in, unsigned short* __restrict__ out) {
    size_t i = ((size_t)blockIdx.x * 256 + threadIdx.x) * 8;
    float4 a = *(const float4*)(in + i);
    float4 b = *(const float4*)(in + i + 4);
    bf8 v = { (short)f2bf(a.x), (short)f2bf(a.y), (short)f2bf(a.z), (short)f2bf(a.w),
              (short)f2bf(b.x), (short)f2bf(b.y), (short)f2bf(b.z), (short)f2bf(b.w) };
    *(bf8*)(out + i) = v;
}

// ---------------------------------------------------------------- fused GEMM: M=32768, N=512, K=1024
// 128x128 tile, BK=32, 4 waves (2x2), grid 1024, XCD-chunked. 3 LDS buffers, prefetch
// depth 2, and the ENTIRE LDS-read/wait/barrier path in inline asm so the compiler's
// waitcnt pass cannot insert a conservative vmcnt(0) before the ds_reads (r10 theory:
// C++-level ds_reads aliasing outstanding global_load_lds forced full drains every step).
// Per step: issue gl_lds(t+2) -> asm ds_read_b128 x8 (tile t) -> lgkmcnt(0)+sched_barrier
// -> 16 MFMA -> vmcnt(4) (tile t+1 landed, t+2 in flight) -> raw s_barrier.
__global__ __launch_bounds__(256, 3) void gemm_asm_kernel(
        const unsigned short* __restrict__ hb, const unsigned short* __restrict__ wb,
        const float* __restrict__ c2, const float* __restrict__ u_w,
        float* __restrict__ beta) {
    __shared__ __align__(16) unsigned short As[3][128 * 32];   // 24 KB
    __shared__ __align__(16) unsigned short Bs[3][128 * 32];   // 24 KB

    const int id = (int)blockIdx.x;                 // 0..1023
    const int wg = (id & 7) * 128 + (id >> 3);      // XCD-chunked (1024 % 8 == 0 -> bijective)
    const int mt = wg >> 2, nt = wg & 3;
    const int m0 = mt * 128, n0 = nt * 128;

    const int tid = (int)threadIdx.x;
    const int wid = tid >> 6, lane = tid & 63;
    const int wr = (wid >> 1) * 64, wc = (wid & 1) * 64;
    const int col = lane & 15, rg = lane >> 4;
    const int rswz = rg ^ ((col >> 1) & 3);         // read slot (row bases are 0 mod 16)

    f4 acc[4][4] = {};

    // staging: row = tid>>2 (0..63; +64 on 2nd call), source slot pre-swizzled
    const int srow = tid >> 2;
    const int sslot = (tid & 3) ^ ((tid >> 3) & 3);
    const unsigned short* Agl = hb + (size_t)(m0 + srow) * H2 + sslot * 8;
    const unsigned short* Bgl = wb + (size_t)(n0 + srow) * H2 + sslot * 8;
    const int ldsb = wid * 512;   // elems; HW adds lane*16B; 2nd 64-row chunk at +2048

    // per-thread read offsets (elements) within a buffer
    const int aoff = (wr + col) * 32 + rswz * 8;    // + i*16*32 per fragment
    const int boff = (wc + col) * 32 + rswz * 8;

    // ---- prologue: stage tiles 0 and 1 (8 loads)
    #pragma unroll
    for (int p = 0; p < 2; ++p) {
        const int k0 = p * 32;
        gl_lds16(Agl + k0,                   &As[p][ldsb]);
        gl_lds16(Agl + k0 + (size_t)64 * H2, &As[p][ldsb + 2048]);
        gl_lds16(Bgl + k0,                   &Bs[p][ldsb]);
        gl_lds16(Bgl + k0 + (size_t)64 * H2, &Bs[p][ldsb + 2048]);
    }
    asm volatile("s_waitcnt vmcnt(4)" ::: "memory");   // tile 0 landed (tile 1 in flight)
    __builtin_amdgcn_s_barrier();

    int cur = 0;
    for (int t = 0; t < 32; ++t) {
        // ---- issue tile t+2 into the third buffer
        if (t < 30) {
            int wrb = cur + 2; if (wrb >= 3) wrb -= 3;
            const int kn = (t + 2) * 32;
            gl_lds16(Agl + kn,                   &As[wrb][ldsb]);
            gl_lds16(Agl + kn + (size_t)64 * H2, &As[wrb][ldsb + 2048]);
            gl_lds16(Bgl + kn,                   &Bs[wrb][ldsb]);
            gl_lds16(Bgl + kn + (size_t)64 * H2, &Bs[wrb][ldsb + 2048]);
        }
        __builtin_amdgcn_sched_barrier(0);   // pin prefetch issues above the reads
        // ---- asm ds_read of tile t (compiler cannot insert vmcnt waits here)
        bf8 av[4], bv[4];
        {
            lds_cp pA = (lds_cp)&As[cur][0] + aoff;
            lds_cp pB = (lds_cp)&Bs[cur][0] + boff;
            #pragma unroll
            for (int i = 0; i < 4; ++i)
                asm volatile("ds_read_b128 %0, %1" : "=&v"(av[i]) : "v"(pA + i * 512));
            #pragma unroll
            for (int i = 0; i < 4; ++i)
                asm volatile("ds_read_b128 %0, %1" : "=&v"(bv[i]) : "v"(pB + i * 512));
        }
        asm volatile("s_waitcnt lgkmcnt(0)" ::: "memory");
        __builtin_amdgcn_sched_barrier(0);   // rule #18: MFMA must not hoist above the wait
        #pragma unroll
        for (int i = 0; i < 4; ++i)
            #pragma unroll
            for (int j = 0; j < 4; ++j)
                acc[i][j] = __builtin_amdgcn_mfma_f32_16x16x32_bf16(av[i], bv[j], acc[i][j], 0, 0, 0);
        // ---- wait only tile t+1's loads (counted), then raw barrier
        if (t < 30) asm volatile("s_waitcnt vmcnt(4)" ::: "memory");
        else        asm volatile("s_waitcnt vmcnt(0)" ::: "memory");
        __builtin_amdgcn_s_barrier();
        cur = (cur == 2) ? 0 : cur + 1;
    }

    // ---- epilogue: beta[m] += sum_n tanh(acc + c2[n]) * u[n] over this wave's 64-col strip
    const int b_idx = mt >> 2;                      // m0 / Ss
    const float* c2b = c2 + (size_t)b_idx * ATT + n0 + wc;
    const float* ub  = u_w + n0 + wc;
    float rp[4][4] = {};
    #pragma unroll
    for (int j = 0; j < 4; ++j) {
        int n = j * 16 + col;
        float cv = c2b[n];
        float uv = ub[n];
        #pragma unroll
        for (int i = 0; i < 4; ++i)
            #pragma unroll
            for (int r = 0; r < 4; ++r)
                rp[i][r] += tanh_fast(acc[i][j][r] + cv) * uv;
    }
    #pragma unroll
    for (int i = 0; i < 4; ++i)
        #pragma unroll
        for (int r = 0; r < 4; ++r) {
            float v = rp[i][r];
            v += __shfl_xor(v, 1);
            v += __shfl_xor(v, 2);
            v += __shfl_xor(v, 4);
            v += __shfl_xor(v, 8);
            if (col == 0)
                atomicAdd(&beta[(size_t)m0 + wr + i * 16 + rg * 4 + r], v);
        }
}

// ---------------------------------------------------------------- fused masked-softmax + weighted sum
// grid (Bb, 8): block (b, sc) recomputes the tiny softmax for batch b (LDS), then
// accumulates its 64-s chunk of s[b,d] = sum_s alpha*h_bf via atomics.
__global__ __launch_bounds__(256) void wsum2_kernel(
        const unsigned short* __restrict__ hb, const float* __restrict__ beta,
        const int* __restrict__ h_mask, float* __restrict__ out) {
    __shared__ float red[8];
    __shared__ float al[64];
    const int b = (int)blockIdx.x;
    const int sc = (int)blockIdx.y;
    const int tid = (int)threadIdx.x;
    const int lane = tid & 63, wave = tid >> 6;

    const float* bp = beta + (size_t)b * Ss;
    const int* mp = h_mask + (size_t)b * Ss;
    float v1 = mp[tid]       ? bp[tid]       : -1e20f;
    float v2 = mp[tid + 256] ? bp[tid + 256] : -1e20f;
    float mx = fmaxf(v1, v2);
    #pragma unroll
    for (int off = 32; off >= 1; off >>= 1) mx = fmaxf(mx, __shfl_xor(mx, off, 64));
    if (lane == 0) red[wave] = mx;
    __syncthreads();
    mx = fmaxf(fmaxf(red[0], red[1]), fmaxf(red[2], red[3]));
    float e1 = __expf(v1 - mx), e2 = __expf(v2 - mx);
    float sm = e1 + e2;
    #pragma unroll
    for (int off = 32; off >= 1; off >>= 1) sm += __shfl_xor(sm, off, 64);
    if (lane == 0) red[4 + wave] = sm;
    __syncthreads();
    const float inv = 1.0f / ((red[4] + red[5]) + (red[6] + red[7]));
    int ls1 = tid - sc * 64, ls2 = tid + 256 - sc * 64;
    if ((unsigned)ls1 < 64u) al[ls1] = e1 * inv;
    if ((unsigned)ls2 < 64u) al[ls2] = e2 * inv;
    __syncthreads();

    const int g = tid >> 7, t = tid & 127;     // s-half (32) x dim-group (8 dims)
    const int d0 = t * 8, si = g * 32;
    const unsigned short* hp = hb + ((size_t)b * Ss + sc * 64 + si) * H2 + d0;
    float acc[8] = {};
    #pragma unroll 4
    for (int s = 0; s < 32; ++s) {
        bf8 v = *(const bf8*)(hp + (size_t)s * H2);
        float a = al[si + s];
        #pragma unroll
        for (int j = 0; j < 8; ++j) {
            float hv = __uint_as_float(((unsigned)(unsigned short)v[j]) << 16);
            acc[j] = fmaf(a, hv, acc[j]);
        }
    }
    #pragma unroll
    for (int j = 0; j < 8; ++j)
        atomicAdd(&out[(size_t)b * H2 + d0 + j], acc[j]);
}

// ---------------------------------------------------------------- launch
extern "C" void kernel_launch(void* const* d_in, const int* in_sizes, int n_in,
                              void* d_out, int out_size, void* d_ws, size_t ws_size,
                              hipStream_t stream) {
    const float* h      = (const float*)d_in[0];
    const int*   h_mask = (const int*)d_in[1];
    const float* ht     = (const float*)d_in[2];
    const float* w1_w   = (const float*)d_in[3];
    const float* w1_b   = (const float*)d_in[4];
    const float* u_w    = (const float*)d_in[5];
    float* out = (float*)d_out;

    float* ws      = (float*)d_ws;
    float* ht_mean = ws;                 // 65536 floats
    float* c2      = ws + 65536;         // 32768
    float* beta    = ws + 98304;         // 32768
    unsigned short* w1a_bf = (unsigned short*)((char*)d_ws + 659456);            // 1 MB
    unsigned short* h_bf   = (unsigned short*)((char*)d_ws + 659456 + 1048576);  // 64 MB (ws-fit proven r2)

    hipLaunchKernelGGL(prep_kernel, dim3(704), dim3(256), 0, stream,
                       ht, ht_mean, w1_w, w1a_bf, beta, out);
    hipLaunchKernelGGL(c2_kernel2, dim3(Bb, 8), dim3(256), 0, stream, ht_mean, w1_w, w1_b, c2);
    hipLaunchKernelGGL(convh_kernel, dim3(16384), dim3(256), 0, stream, h, h_bf);
    hipLaunchKernelGGL(gemm_asm_kernel, dim3((MM / 128) * (ATT / 128)), dim3(256), 0, stream,
                       h_bf, w1a_bf, c2, u_w, beta);
    hipLaunchKernelGGL(wsum2_kernel, dim3(Bb, 8), dim3(256), 0, stream, h_bf, beta, h_mask, out);
}